// Round 2
// baseline (18212.268 us; speedup 1.0000x reference)
//
#include <hip/hip_runtime.h>
#include <stdint.h>
#include <stddef.h>

// ---------------- problem constants ----------------
static constexpr int  T_STEPS   = 2048;
static constexpr int  BATCH     = 16;
static constexpr int  DIM       = 1024;
static constexpr long RROWS     = (long)T_STEPS * BATCH;   // 32768 rows of x
static constexpr long BD        = (long)BATCH * DIM;       // 16384
static constexpr long OUT_ELEMS = (long)T_STEPS * BD;      // 33554432

// ---------------- ws layout (bytes) ----------------
static constexpr size_t WX_OFF  = 0;
static constexpr size_t XBF_OFF = 134217728;
static constexpr size_t WHI_OFF = XBF_OFF + 67108864;   // 201326592
static constexpr size_t WLO_OFF = WHI_OFF + 6291456;    // 207618048
static constexpr size_t HBH_OFF = WLO_OFF + 6291456;    // 213909504
static constexpr size_t HBL_OFF = HBH_OFF + 65536;      // 213975040
static constexpr size_t FLG_OFF = HBL_OFF + 65536;      // 214040576  (256 ints)

typedef __attribute__((ext_vector_type(4))) float          f32x4;
typedef __attribute__((ext_vector_type(8))) short          s16x8;
typedef __attribute__((ext_vector_type(4))) unsigned short u16x4;
typedef __attribute__((ext_vector_type(8))) unsigned short u16x8;

#define AS1 __attribute__((address_space(1)))
#define AS3 __attribute__((address_space(3)))

// ---------------- helpers ----------------
static __device__ __forceinline__ unsigned short f2bf(float x) {
  union { float f; unsigned u; } a; a.f = x;
  unsigned r = a.u + 0x7fffu + ((a.u >> 16) & 1u);
  return (unsigned short)(r >> 16);
}
static __device__ __forceinline__ float bf2f(unsigned short h) {
  union { unsigned u; float f; } a; a.u = ((unsigned)h) << 16; return a.f;
}
static __device__ __forceinline__ void gload_lds16(const void* g, void* l) {
  __builtin_amdgcn_global_load_lds((const AS1 void*)g, (AS3 void*)l, 16, 0, 0);
}

// ---------------- convert x -> bf16 ----------------
__global__ __launch_bounds__(256) void convert_x_kernel(const float* __restrict__ x,
                                                        unsigned short* __restrict__ xbf) {
  const long n8 = (RROWS * DIM) / 8;
  const long stride = (long)gridDim.x * blockDim.x;
  for (long i = (long)blockIdx.x * blockDim.x + threadIdx.x; i < n8; i += stride) {
    const float4* p = (const float4*)(x + i * 8);
    float4 v0 = p[0], v1 = p[1];
    u16x8 o;
    o[0] = f2bf(v0.x); o[1] = f2bf(v0.y); o[2] = f2bf(v0.z); o[3] = f2bf(v0.w);
    o[4] = f2bf(v1.x); o[5] = f2bf(v1.y); o[6] = f2bf(v1.z); o[7] = f2bf(v1.w);
    *(u16x8*)(xbf + i * 8) = o;
  }
}

// ---------------- convert [W_alpha;W_beta;W_x] -> bf16 hi/lo split ----------------
__global__ __launch_bounds__(256) void convert_w_kernel(const float* __restrict__ Wa,
                                                        const float* __restrict__ Wb,
                                                        const float* __restrict__ Wx,
                                                        unsigned short* __restrict__ whi,
                                                        unsigned short* __restrict__ wlo) {
  const long n4 = (3l * 1024 * 1024) / 4;
  const long stride = (long)gridDim.x * blockDim.x;
  for (long i = (long)blockIdx.x * blockDim.x + threadIdx.x; i < n4; i += stride) {
    long e = i * 4;
    int mat = (int)(e >> 20);
    long off = e & 1048575l;
    const float* src = (mat == 0) ? Wa : (mat == 1) ? Wb : Wx;
    float4 v = *(const float4*)(src + off);
    u16x4 hi, lo;
    hi[0] = f2bf(v.x); lo[0] = f2bf(v.x - bf2f(hi[0]));
    hi[1] = f2bf(v.y); lo[1] = f2bf(v.y - bf2f(hi[1]));
    hi[2] = f2bf(v.z); lo[2] = f2bf(v.z - bf2f(hi[2]));
    hi[3] = f2bf(v.w); lo[3] = f2bf(v.w - bf2f(hi[3]));
    *(u16x4*)(whi + e) = hi;
    *(u16x4*)(wlo + e) = lo;
  }
}

// ---------------- fused pre-GEMM: alpha/beta/wx = act(x @ Wcat^T + bias) ----------------
__global__ __launch_bounds__(256) void gemm_pre(
    const unsigned short* __restrict__ xbf,
    const unsigned short* __restrict__ whi,
    const unsigned short* __restrict__ wlo,
    const float* __restrict__ b_alpha, const float* __restrict__ b_beta, const float* __restrict__ b_x,
    float* __restrict__ alpha_dst, float* __restrict__ beta_dst, float* __restrict__ wx_dst)
{
  __shared__ unsigned short Al[128 * 64];
  __shared__ unsigned short Bh[128 * 64];
  __shared__ unsigned short Bl[128 * 64];
  const int tid  = threadIdx.x;
  const int lane = tid & 63;
  const int w    = tid >> 6;
  const int wm   = w >> 1, wn = w & 1;
  const long rowA0 = (long)blockIdx.x * 128;
  const int  colB0 = blockIdx.y * 128;

  f32x4 acc[4][4];
#pragma unroll
  for (int i = 0; i < 4; ++i)
#pragma unroll
    for (int j = 0; j < 4; ++j) acc[i][j] = (f32x4){0.f, 0.f, 0.f, 0.f};

  for (int k0 = 0; k0 < 1024; k0 += 64) {
#pragma unroll
    for (int is = 0; is < 4; ++is) {
      const int o   = is * 4096 + tid * 16;
      const int row = o >> 7;
      const int ke  = (o & 127) >> 1;
      const long asrc = (rowA0 + row) * 1024 + (k0 + ke);
      const long bsrc = ((long)(colB0 + row)) * 1024 + (k0 + ke);
      gload_lds16(xbf + asrc, (char*)Al + is * 4096 + w * 1024);
      gload_lds16(whi + bsrc, (char*)Bh + is * 4096 + w * 1024);
      gload_lds16(wlo + bsrc, (char*)Bl + is * 4096 + w * 1024);
    }
    asm volatile("s_waitcnt vmcnt(0)" ::: "memory");
    __syncthreads();
#pragma unroll
    for (int kk = 0; kk < 2; ++kk) {
      const int koff = kk * 64 + ((lane >> 4) * 16);
      s16x8 a[4], bhf[4], blf[4];
#pragma unroll
      for (int i = 0; i < 4; ++i)
        a[i] = *(const s16x8*)((const char*)Al + (wm * 64 + i * 16 + (lane & 15)) * 128 + koff);
#pragma unroll
      for (int j = 0; j < 4; ++j) {
        const int r = (wn * 64 + j * 16 + (lane & 15)) * 128 + koff;
        bhf[j] = *(const s16x8*)((const char*)Bh + r);
        blf[j] = *(const s16x8*)((const char*)Bl + r);
      }
#pragma unroll
      for (int i = 0; i < 4; ++i)
#pragma unroll
        for (int j = 0; j < 4; ++j) {
          acc[i][j] = __builtin_amdgcn_mfma_f32_16x16x32_bf16(a[i], bhf[j], acc[i][j], 0, 0, 0);
          acc[i][j] = __builtin_amdgcn_mfma_f32_16x16x32_bf16(a[i], blf[j], acc[i][j], 0, 0, 0);
        }
    }
    __syncthreads();
  }

  const int region = colB0 >> 10;
  const float* bias = (region == 0) ? b_alpha : (region == 1) ? b_beta : b_x;
  float* dst = (region == 0) ? alpha_dst : (region == 1) ? beta_dst : wx_dst;
#pragma unroll
  for (int j = 0; j < 4; ++j) {
    const int colg = colB0 + wn * 64 + j * 16 + (lane & 15);
    const int nl = colg & 1023;
    const float bj = bias[nl];
#pragma unroll
    for (int i = 0; i < 4; ++i) {
#pragma unroll
      for (int r = 0; r < 4; ++r) {
        const long rowg = rowA0 + wm * 64 + i * 16 + ((lane >> 4) * 4) + r;
        float z = acc[i][j][r] + bj;
        float val = (region == 2) ? z : (1.0f / (1.0f + __expf(-z)));
        dst[rowg * 1024 + nl] = val;
      }
    }
  }
}

// ---------------- persistent scan kernel ----------------
// 64 WGs x 256 threads. WG wg owns output channels [wg*16, wg*16+16).
// Protocol (all RELAXED agent-scope atomics — no release/acquire, so no
// per-step buffer_wbl2/buffer_inv L2 maintenance on the critical path):
//   publish h via sc-coherent atomic stores -> s_waitcnt vmcnt(0) ->
//   relaxed per-WAVE flag store. Consumers poll all 256 wave-flags
//   (control dependency orders the subsequent h loads).
static __device__ __forceinline__ void publish_h(unsigned short* __restrict__ bhi,
                                                 unsigned short* __restrict__ blo,
                                                 int buf, int b, int n, float hn, int tid) {
  unsigned short hi = f2bf(hn);
  unsigned short lo = f2bf(hn - bf2f(hi));
  int hv = hi, lv = lo;
  int hn2 = __shfl_xor(hv, 1);
  int ln2 = __shfl_xor(lv, 1);
  if (!(tid & 1)) {   // even thread stores packed {n, n+1}
    unsigned ph = (unsigned)hv | ((unsigned)hn2 << 16);
    unsigned pl = (unsigned)lv | ((unsigned)ln2 << 16);
    long base = (long)buf * BD + (long)b * DIM + n;
    __hip_atomic_store((unsigned*)(bhi + base), ph, __ATOMIC_RELAXED, __HIP_MEMORY_SCOPE_AGENT);
    __hip_atomic_store((unsigned*)(blo + base), pl, __ATOMIC_RELAXED, __HIP_MEMORY_SCOPE_AGENT);
  }
}

static __device__ __forceinline__ void spin_all(const int* __restrict__ flags, int tgt, int lane) {
  const int* p = flags + lane * 4;   // 64 lanes x 4 flags = 256 wave-flags
  int iters = 0;
  while (true) {
    int f0 = __hip_atomic_load(p + 0, __ATOMIC_RELAXED, __HIP_MEMORY_SCOPE_AGENT);
    int f1 = __hip_atomic_load(p + 1, __ATOMIC_RELAXED, __HIP_MEMORY_SCOPE_AGENT);
    int f2 = __hip_atomic_load(p + 2, __ATOMIC_RELAXED, __HIP_MEMORY_SCOPE_AGENT);
    int f3 = __hip_atomic_load(p + 3, __ATOMIC_RELAXED, __HIP_MEMORY_SCOPE_AGENT);
    int m01 = f0 < f1 ? f0 : f1;
    int m23 = f2 < f3 ? f2 : f3;
    int m   = m01 < m23 ? m01 : m23;
    if (__all(m >= tgt)) break;
    if (++iters > (1 << 18)) break;   // safety valve: wrong answer beats a hang
  }
}

__global__ __launch_bounds__(256) void scan_kernel(
    const float* __restrict__ Wh,
    const float* __restrict__ h0,
    const float* __restrict__ wxb,
    float* __restrict__ out_buf,     // d_out: out region; beta pre-stored here
    float* __restrict__ h_out,       // d_out + OUT_ELEMS: h region; alpha pre-stored at +BD
    unsigned short* __restrict__ hbh,
    unsigned short* __restrict__ hbl,
    int* __restrict__ flags)
{
  const int tid  = threadIdx.x;
  const int lane = tid & 63;
  const int w    = tid >> 6;
  const int wg   = blockIdx.x;
  const int n0   = wg * 16;

  __shared__ unsigned short WhiL[16 * 1024];
  __shared__ unsigned short WloL[16 * 1024];
  __shared__ float zred[4][256];

  // ---- stage W_h slice into LDS (hi/lo, XOR-swizzled) ----
  {
    const int row = tid >> 4;
    const int kb  = (tid & 15) * 64;
    const float* src = Wh + (size_t)(n0 + row) * 1024 + kb;
    const unsigned sx = ((unsigned)(row & 7)) << 4;
    const unsigned rb = (unsigned)row * 2048u;
#pragma unroll
    for (int q = 0; q < 16; ++q) {
      float4 v = *(const float4*)(src + q * 4);
      u16x4 hi, lo;
      hi[0] = f2bf(v.x); lo[0] = f2bf(v.x - bf2f(hi[0]));
      hi[1] = f2bf(v.y); lo[1] = f2bf(v.y - bf2f(hi[1]));
      hi[2] = f2bf(v.z); lo[2] = f2bf(v.z - bf2f(hi[2]));
      hi[3] = f2bf(v.w); lo[3] = f2bf(v.w - bf2f(hi[3]));
      const unsigned addr = (rb + (unsigned)(kb + q * 4) * 2u) ^ sx;
      *(u16x4*)((char*)WhiL + addr) = hi;
      *(u16x4*)((char*)WloL + addr) = lo;
    }
  }

  const int b_own  = tid >> 4;
  const int nl_own = tid & 15;
  const long off_own = (long)b_own * 1024 + n0 + nl_own;

  // ---- phase 0: h[0] = h0, publish into buf 0, raise per-wave flag = 1 ----
  float hprev = h0[off_own];
  h_out[off_own] = hprev;
  publish_h(hbh, hbl, 0, b_own, n0 + nl_own, hprev, tid);
  asm volatile("s_waitcnt vmcnt(0)" ::: "memory");
  if (lane == 0)
    __hip_atomic_store(&flags[wg * 4 + w], 1, __ATOMIC_RELAXED, __HIP_MEMORY_SCOPE_AGENT);
  __syncthreads();   // W_h LDS staging complete

  // triple for t=0 (alpha pre-stored in h[t+1] slots, beta in out[t] slots)
  float alpha_c = h_out[BD + off_own];
  float beta_c  = out_buf[off_own];
  float wx_c    = wxb[off_own];

  const int arow = lane & 15;                      // batch (A row) / channel (B col)
  const int kq   = w * 256 + ((lane >> 4) * 8);    // wave's K-quarter, lane's k base
  const unsigned bswz = ((unsigned)(arow & 7)) << 4;
  const unsigned brow = (unsigned)arow * 2048u;

  for (int t = 0; t < T_STEPS; ++t) {
    // prefetch next step's alpha/beta/wx FIRST (HBM latency hides under the spin)
    float a_n = 0.f, b_n = 0.f, w_n = 0.f;
    if (t + 1 < T_STEPS) {
      const long o = (long)(t + 1) * BD + off_own;
      a_n = h_out[BD + o];
      b_n = out_buf[o];
      w_n = wxb[o];
    }

    // wait until all 256 waves have published h[t]
    spin_all(flags, t + 1, lane);

    const unsigned short* cur_hi = hbh + (size_t)(t & 1) * BD;
    const unsigned short* cur_lo = hbl + (size_t)(t & 1) * BD;

    // ---- z = h_prev @ Wh_slice^T  (3-term bf16 split, K split across 4 waves) ----
    f32x4 acc0 = (f32x4){0.f,0.f,0.f,0.f};
    f32x4 acc1 = (f32x4){0.f,0.f,0.f,0.f};
    f32x4 acc2 = (f32x4){0.f,0.f,0.f,0.f};
    union AB { unsigned long long u[2]; s16x8 v; };
    s16x8 ahi[8], alo8[8];
#pragma unroll
    for (int s = 0; s < 8; ++s) {
      const int ko = kq + s * 32;
      const unsigned long long* ph = (const unsigned long long*)(cur_hi + (arow << 10) + ko);
      const unsigned long long* pl = (const unsigned long long*)(cur_lo + (arow << 10) + ko);
      AB th, tl;
      th.u[0] = __hip_atomic_load(ph,     __ATOMIC_RELAXED, __HIP_MEMORY_SCOPE_AGENT);
      th.u[1] = __hip_atomic_load(ph + 1, __ATOMIC_RELAXED, __HIP_MEMORY_SCOPE_AGENT);
      tl.u[0] = __hip_atomic_load(pl,     __ATOMIC_RELAXED, __HIP_MEMORY_SCOPE_AGENT);
      tl.u[1] = __hip_atomic_load(pl + 1, __ATOMIC_RELAXED, __HIP_MEMORY_SCOPE_AGENT);
      ahi[s] = th.v; alo8[s] = tl.v;
    }
#pragma unroll
    for (int s = 0; s < 8; ++s) {
      const int ko = kq + s * 32;
      const unsigned baddr = (brow + (unsigned)ko * 2u) ^ bswz;
      s16x8 bh = *(const s16x8*)((const char*)WhiL + baddr);
      s16x8 bl = *(const s16x8*)((const char*)WloL + baddr);
      acc0 = __builtin_amdgcn_mfma_f32_16x16x32_bf16(ahi[s],  bh, acc0, 0, 0, 0);
      acc1 = __builtin_amdgcn_mfma_f32_16x16x32_bf16(ahi[s],  bl, acc1, 0, 0, 0);
      acc2 = __builtin_amdgcn_mfma_f32_16x16x32_bf16(alo8[s], bh, acc2, 0, 0, 0);
    }
    f32x4 zp = acc0 + acc1 + acc2;
#pragma unroll
    for (int r = 0; r < 4; ++r) {
      const int bidx = (lane >> 4) * 4 + r;
      zred[w][bidx * 16 + arow] = zp[r];
    }
    __syncthreads();   // the only per-step barrier (zred reduction)

    // ---- elementwise update (thread owns (b_own, n0+nl_own)) ----
    const float z  = zred[0][tid] + zred[1][tid] + zred[2][tid] + zred[3][tid] + wx_c;
    const float v  = tanhf(z);
    const float hn = alpha_c * hprev + beta_c * v;
    const long o = (long)t * BD + off_own;
    h_out[BD + o] = hn;                              // h[t+1]
    const float sg = 1.0f / (1.0f + __expf(-hn));
    out_buf[o] = hn * hn * sg;                       // out[t] = hn*silu(hn)

    if (t + 1 < T_STEPS) {
      publish_h(hbh, hbl, (t + 1) & 1, b_own, n0 + nl_own, hn, tid);
      asm volatile("s_waitcnt vmcnt(0)" ::: "memory");   // publishes (and stores) complete
      if (lane == 0)
        __hip_atomic_store(&flags[wg * 4 + w], t + 2, __ATOMIC_RELAXED, __HIP_MEMORY_SCOPE_AGENT);
    }
    hprev = hn;
    alpha_c = a_n; beta_c = b_n; wx_c = w_n;
  }
}

// ---------------- launch ----------------
extern "C" void kernel_launch(void* const* d_in, const int* in_sizes, int n_in,
                              void* d_out, int out_size, void* d_ws, size_t ws_size,
                              hipStream_t stream) {
  const float* x  = (const float*)d_in[0];
  const float* h0 = (const float*)d_in[1];
  const float* Wa = (const float*)d_in[2];
  const float* ba = (const float*)d_in[3];
  const float* Wb = (const float*)d_in[4];
  const float* bb = (const float*)d_in[5];
  const float* Wh = (const float*)d_in[6];
  const float* Wx = (const float*)d_in[7];
  const float* bx = (const float*)d_in[8];

  float* out_buf = (float*)d_out;
  float* h_out   = out_buf + OUT_ELEMS;

  char* ws = (char*)d_ws;
  float*          wx_buf = (float*)(ws + WX_OFF);
  unsigned short* xbf    = (unsigned short*)(ws + XBF_OFF);
  unsigned short* whi    = (unsigned short*)(ws + WHI_OFF);
  unsigned short* wlo    = (unsigned short*)(ws + WLO_OFF);
  unsigned short* hbh    = (unsigned short*)(ws + HBH_OFF);
  unsigned short* hbl    = (unsigned short*)(ws + HBL_OFF);
  int*            flags  = (int*)(ws + FLG_OFF);

  hipMemsetAsync(flags, 0, 1024, stream);
  convert_x_kernel<<<4096, 256, 0, stream>>>(x, xbf);
  convert_w_kernel<<<1024, 256, 0, stream>>>(Wa, Wb, Wx, whi, wlo);
  gemm_pre<<<dim3(256, 24), 256, 0, stream>>>(xbf, whi, wlo, ba, bb, bx,
                                              h_out + BD, out_buf, wx_buf);
  scan_kernel<<<64, 256, 0, stream>>>(Wh, h0, wx_buf, out_buf, h_out, hbh, hbl, flags);
}

// Round 5
// 14165.404 us; speedup vs baseline: 1.2857x; 1.2857x over previous
//
#include <hip/hip_runtime.h>
#include <stdint.h>
#include <stddef.h>

// ---------------- problem constants ----------------
static constexpr int  T_STEPS   = 2048;
static constexpr int  BATCH     = 16;
static constexpr int  DIM       = 1024;
static constexpr long RROWS     = (long)T_STEPS * BATCH;   // 32768 rows of x
static constexpr long BD        = (long)BATCH * DIM;       // 16384
static constexpr long OUT_ELEMS = (long)T_STEPS * BD;      // 33554432

// ---------------- ws layout (bytes) ----------------
static constexpr size_t WX_OFF  = 0;
static constexpr size_t XBF_OFF = 134217728;
static constexpr size_t WHI_OFF = XBF_OFF + 67108864;   // 201326592
static constexpr size_t WLO_OFF = WHI_OFF + 6291456;    // 207618048
static constexpr size_t HBP_OFF = WLO_OFF + 6291456;    // 213909504: packed h [2][B][D] u32

typedef __attribute__((ext_vector_type(4))) float          f32x4;
typedef __attribute__((ext_vector_type(8))) short          s16x8;
typedef __attribute__((ext_vector_type(4))) unsigned short u16x4;
typedef __attribute__((ext_vector_type(8))) unsigned short u16x8;

#define AS1 __attribute__((address_space(1)))
#define AS3 __attribute__((address_space(3)))

// ---------------- helpers ----------------
static __device__ __forceinline__ unsigned short f2bf(float x) {
  union { float f; unsigned u; } a; a.f = x;
  unsigned r = a.u + 0x7fffu + ((a.u >> 16) & 1u);
  return (unsigned short)(r >> 16);
}
static __device__ __forceinline__ float bf2f(unsigned short h) {
  union { unsigned u; float f; } a; a.u = ((unsigned)h) << 16; return a.f;
}
static __device__ __forceinline__ void gload_lds16(const void* g, void* l) {
  __builtin_amdgcn_global_load_lds((const AS1 void*)g, (AS3 void*)l, 16, 0, 0);
}
// packed h word: {bf16 hi | bf16 lo with 2 LSBs replaced by epoch tag}
static __device__ __forceinline__ unsigned pack_h(float hn, unsigned tag) {
  unsigned short hi = f2bf(hn);
  unsigned short lo = f2bf(hn - bf2f(hi));
  return ((unsigned)hi << 16) | (unsigned)(lo & 0xFFFCu) | tag;
}

// ---------------- convert x -> bf16 ----------------
__global__ __launch_bounds__(256) void convert_x_kernel(const float* __restrict__ x,
                                                        unsigned short* __restrict__ xbf) {
  const long n8 = (RROWS * DIM) / 8;
  const long stride = (long)gridDim.x * blockDim.x;
  for (long i = (long)blockIdx.x * blockDim.x + threadIdx.x; i < n8; i += stride) {
    const float4* p = (const float4*)(x + i * 8);
    float4 v0 = p[0], v1 = p[1];
    u16x8 o;
    o[0] = f2bf(v0.x); o[1] = f2bf(v0.y); o[2] = f2bf(v0.z); o[3] = f2bf(v0.w);
    o[4] = f2bf(v1.x); o[5] = f2bf(v1.y); o[6] = f2bf(v1.z); o[7] = f2bf(v1.w);
    *(u16x8*)(xbf + i * 8) = o;
  }
}

// ---------------- convert [W_alpha;W_beta;W_x] -> bf16 hi/lo split ----------------
__global__ __launch_bounds__(256) void convert_w_kernel(const float* __restrict__ Wa,
                                                        const float* __restrict__ Wb,
                                                        const float* __restrict__ Wx,
                                                        unsigned short* __restrict__ whi,
                                                        unsigned short* __restrict__ wlo) {
  const long n4 = (3l * 1024 * 1024) / 4;
  const long stride = (long)gridDim.x * blockDim.x;
  for (long i = (long)blockIdx.x * blockDim.x + threadIdx.x; i < n4; i += stride) {
    long e = i * 4;
    int mat = (int)(e >> 20);
    long off = e & 1048575l;
    const float* src = (mat == 0) ? Wa : (mat == 1) ? Wb : Wx;
    float4 v = *(const float4*)(src + off);
    u16x4 hi, lo;
    hi[0] = f2bf(v.x); lo[0] = f2bf(v.x - bf2f(hi[0]));
    hi[1] = f2bf(v.y); lo[1] = f2bf(v.y - bf2f(hi[1]));
    hi[2] = f2bf(v.z); lo[2] = f2bf(v.z - bf2f(hi[2]));
    hi[3] = f2bf(v.w); lo[3] = f2bf(v.w - bf2f(hi[3]));
    *(u16x4*)(whi + e) = hi;
    *(u16x4*)(wlo + e) = lo;
  }
}

// ---------------- fused pre-GEMM: alpha/beta/wx = act(x @ Wcat^T + bias) ----------------
__global__ __launch_bounds__(256) void gemm_pre(
    const unsigned short* __restrict__ xbf,
    const unsigned short* __restrict__ whi,
    const unsigned short* __restrict__ wlo,
    const float* __restrict__ b_alpha, const float* __restrict__ b_beta, const float* __restrict__ b_x,
    float* __restrict__ alpha_dst, float* __restrict__ beta_dst, float* __restrict__ wx_dst)
{
  __shared__ unsigned short Al[128 * 64];
  __shared__ unsigned short Bh[128 * 64];
  __shared__ unsigned short Bl[128 * 64];
  const int tid  = threadIdx.x;
  const int lane = tid & 63;
  const int w    = tid >> 6;
  const int wm   = w >> 1, wn = w & 1;
  const long rowA0 = (long)blockIdx.x * 128;
  const int  colB0 = blockIdx.y * 128;

  f32x4 acc[4][4];
#pragma unroll
  for (int i = 0; i < 4; ++i)
#pragma unroll
    for (int j = 0; j < 4; ++j) acc[i][j] = (f32x4){0.f, 0.f, 0.f, 0.f};

  for (int k0 = 0; k0 < 1024; k0 += 64) {
#pragma unroll
    for (int is = 0; is < 4; ++is) {
      const int o   = is * 4096 + tid * 16;
      const int row = o >> 7;
      const int ke  = (o & 127) >> 1;
      const long asrc = (rowA0 + row) * 1024 + (k0 + ke);
      const long bsrc = ((long)(colB0 + row)) * 1024 + (k0 + ke);
      gload_lds16(xbf + asrc, (char*)Al + is * 4096 + w * 1024);
      gload_lds16(whi + bsrc, (char*)Bh + is * 4096 + w * 1024);
      gload_lds16(wlo + bsrc, (char*)Bl + is * 4096 + w * 1024);
    }
    asm volatile("s_waitcnt vmcnt(0)" ::: "memory");
    __syncthreads();
#pragma unroll
    for (int kk = 0; kk < 2; ++kk) {
      const int koff = kk * 64 + ((lane >> 4) * 16);
      s16x8 a[4], bhf[4], blf[4];
#pragma unroll
      for (int i = 0; i < 4; ++i)
        a[i] = *(const s16x8*)((const char*)Al + (wm * 64 + i * 16 + (lane & 15)) * 128 + koff);
#pragma unroll
      for (int j = 0; j < 4; ++j) {
        const int r = (wn * 64 + j * 16 + (lane & 15)) * 128 + koff;
        bhf[j] = *(const s16x8*)((const char*)Bh + r);
        blf[j] = *(const s16x8*)((const char*)Bl + r);
      }
#pragma unroll
      for (int i = 0; i < 4; ++i)
#pragma unroll
        for (int j = 0; j < 4; ++j) {
          acc[i][j] = __builtin_amdgcn_mfma_f32_16x16x32_bf16(a[i], bhf[j], acc[i][j], 0, 0, 0);
          acc[i][j] = __builtin_amdgcn_mfma_f32_16x16x32_bf16(a[i], blf[j], acc[i][j], 0, 0, 0);
        }
    }
    __syncthreads();
  }

  const int region = colB0 >> 10;
  const float* bias = (region == 0) ? b_alpha : (region == 1) ? b_beta : b_x;
  float* dst = (region == 0) ? alpha_dst : (region == 1) ? beta_dst : wx_dst;
#pragma unroll
  for (int j = 0; j < 4; ++j) {
    const int colg = colB0 + wn * 64 + j * 16 + (lane & 15);
    const int nl = colg & 1023;
    const float bj = bias[nl];
#pragma unroll
    for (int i = 0; i < 4; ++i) {
#pragma unroll
      for (int r = 0; r < 4; ++r) {
        const long rowg = rowA0 + wm * 64 + i * 16 + ((lane >> 4) * 4) + r;
        float z = acc[i][j][r] + bj;
        float val = (region == 2) ? z : (1.0f / (1.0f + __expf(-z)));
        dst[rowg * 1024 + nl] = val;
      }
    }
  }
}

// ---------------- persistent scan: data-as-flag protocol ----------------
// 32 WGs x 256 threads; WG owns channels [wg*32, wg*32+32).
// h published as ONE packed u32/element {hi16, lo16 with 2-LSB epoch tag t&3}
// via agent-scope RELAXED atomic stores (round-2-verified primitive). Consumers
// poll their own MFMA fragment words: tags==t&3 across all 64 words => the
// registers already hold the data. No flags, no acks, no release fences.
// Ping-pong buf[t&1] + mod-4 tags: overwrite (t -> t+2) is causally gated on
// every WG's h[t+1] publish, which follows that WG's h[t] loads. Leftover
// tags from a previous replay (2046->2, 2047->3) and 0xAA poison (tag 2)
// all read as stale, so no initialization pass is needed.
__global__ __launch_bounds__(256) void scan_kernel(
    const float* __restrict__ Wh,
    const float* __restrict__ h0,
    const float* __restrict__ wxb,
    float* __restrict__ out_buf,     // d_out: beta pre-stored here
    float* __restrict__ h_out,       // d_out + OUT_ELEMS: alpha pre-stored at +BD
    unsigned* __restrict__ hbp)      // packed h ping-pong [2][B][D]
{
  __shared__ unsigned short WhiL[32 * 1024];
  __shared__ unsigned short WloL[32 * 1024];
  __shared__ float zred[2][4][16][33];

  const int tid  = threadIdx.x;
  const int lane = tid & 63;
  const int w    = tid >> 6;
  const int wg   = blockIdx.x;
  const int n0   = wg * 32;

  // ---- stage W_h slice (32 rows) into LDS, hi/lo bf16, XOR-swizzled ----
  {
    const int row = tid >> 3;            // 0..31
    const int kb  = (tid & 7) * 128;     // 128 elems per thread
    const float* src = Wh + (size_t)(n0 + row) * 1024 + kb;
    const unsigned sx = ((unsigned)(row & 7)) << 4;
    const unsigned rb = (unsigned)row * 2048u;
#pragma unroll
    for (int q = 0; q < 32; ++q) {
      float4 v = *(const float4*)(src + q * 4);
      u16x4 hi, lo;
      hi[0] = f2bf(v.x); lo[0] = f2bf(v.x - bf2f(hi[0]));
      hi[1] = f2bf(v.y); lo[1] = f2bf(v.y - bf2f(hi[1]));
      hi[2] = f2bf(v.z); lo[2] = f2bf(v.z - bf2f(hi[2]));
      hi[3] = f2bf(v.w); lo[3] = f2bf(v.w - bf2f(hi[3]));
      const unsigned addr = (rb + (unsigned)(kb + q * 4) * 2u) ^ sx;
      *(u16x4*)((char*)WhiL + addr) = hi;
      *(u16x4*)((char*)WloL + addr) = lo;
    }
  }

  const int b_own = tid >> 4;            // batch 0..15
  const int nl    = tid & 15;            // channel-within-slice (plus +16 twin)
  const int nabs0 = n0 + nl, nabs1 = n0 + nl + 16;
  const long off0 = (long)b_own * 1024 + nabs0;
  const long off1 = off0 + 16;

  // ---- phase 0: h[0] = h0, publish packed words (tag 0) into buf 0 ----
  float hp0 = h0[off0], hp1 = h0[off1];
  h_out[off0] = hp0; h_out[off1] = hp1;
  {
    unsigned* b0 = hbp + (long)b_own * 1024;
    __hip_atomic_store(&b0[nabs0], pack_h(hp0, 0u), __ATOMIC_RELAXED, __HIP_MEMORY_SCOPE_AGENT);
    __hip_atomic_store(&b0[nabs1], pack_h(hp1, 0u), __ATOMIC_RELAXED, __HIP_MEMORY_SCOPE_AGENT);
  }
  __syncthreads();   // LDS W staging complete

  // gates for t=0 (alpha pre-stored in h[t+1] slots, beta in out[t] slots)
  float a_c0 = h_out[BD + off0], a_c1 = h_out[BD + off1];
  float b_c0 = out_buf[off0],    b_c1 = out_buf[off1];
  float w_c0 = wxb[off0],        w_c1 = wxb[off1];

  const int arow = lane & 15;                      // batch (A row) / channel col
  const int kq   = w * 256 + ((lane >> 4) * 8);    // wave's K-quarter, lane's k base
  const unsigned bswz = ((unsigned)(arow & 7)) << 4;

  for (int t = 0; t < T_STEPS; ++t) {
    // prefetch next step's gates (overlaps the poll)
    float a_n0 = 0.f, a_n1 = 0.f, b_n0 = 0.f, b_n1 = 0.f, w_n0 = 0.f, w_n1 = 0.f;
    if (t + 1 < T_STEPS) {
      const long o = (long)(t + 1) * BD;
      a_n0 = __builtin_nontemporal_load(h_out + BD + o + off0);
      a_n1 = __builtin_nontemporal_load(h_out + BD + o + off1);
      b_n0 = __builtin_nontemporal_load(out_buf + o + off0);
      b_n1 = __builtin_nontemporal_load(out_buf + o + off1);
      w_n0 = __builtin_nontemporal_load(wxb + o + off0);
      w_n1 = __builtin_nontemporal_load(wxb + o + off1);
    }

    // ---- poll own fragment words until every tag == t&3 (data-as-flag) ----
    const unsigned tagt = (unsigned)(t & 3);
    const unsigned* cur = hbp + (size_t)(t & 1) * BD + ((long)arow << 10) + kq;
    unsigned long long v[32];
    {
      int iters = 0;
      while (true) {
        unsigned bad = 0;
#pragma unroll
        for (int s = 0; s < 8; ++s) {
          const unsigned long long* p = (const unsigned long long*)(cur + s * 32);
          v[s*4+0] = __hip_atomic_load(p + 0, __ATOMIC_RELAXED, __HIP_MEMORY_SCOPE_AGENT);
          v[s*4+1] = __hip_atomic_load(p + 1, __ATOMIC_RELAXED, __HIP_MEMORY_SCOPE_AGENT);
          v[s*4+2] = __hip_atomic_load(p + 2, __ATOMIC_RELAXED, __HIP_MEMORY_SCOPE_AGENT);
          v[s*4+3] = __hip_atomic_load(p + 3, __ATOMIC_RELAXED, __HIP_MEMORY_SCOPE_AGENT);
        }
#pragma unroll
        for (int i = 0; i < 32; ++i) {
          bad |= ((unsigned)v[i] ^ tagt) & 3u;
          bad |= ((unsigned)(v[i] >> 32) ^ tagt) & 3u;
        }
        if (__all(bad == 0u)) break;
        if (++iters > 4096) break;   // safety valve: visible failure beats a hang
        __builtin_amdgcn_s_sleep(1);
      }
    }

    // ---- unpack {hi,lo} + z = h @ Wh_slice^T (3-term bf16 split, 2 col-tiles) ----
    f32x4 a0[2], a1[2], a2[2];
#pragma unroll
    for (int j = 0; j < 2; ++j) {
      a0[j] = (f32x4){0.f,0.f,0.f,0.f};
      a1[j] = (f32x4){0.f,0.f,0.f,0.f};
      a2[j] = (f32x4){0.f,0.f,0.f,0.f};
    }
    union Frag { unsigned d[4]; s16x8 h; };
#pragma unroll
    for (int s = 0; s < 8; ++s) {
      Frag fh, fl;
#pragma unroll
      for (int q2 = 0; q2 < 4; ++q2) {
        const unsigned w0 = (unsigned)v[s*4+q2];
        const unsigned w1 = (unsigned)(v[s*4+q2] >> 32);
        fh.d[q2] = (w0 >> 16) | (w1 & 0xFFFF0000u);
        fl.d[q2] = (w0 & 0xFFFCu) | ((w1 & 0xFFFCu) << 16);
      }
      const int ko = kq + s * 32;
#pragma unroll
      for (int j = 0; j < 2; ++j) {
        const unsigned baddr = (((unsigned)(j * 16 + arow)) * 2048u + (unsigned)ko * 2u) ^ bswz;
        s16x8 bh = *(const s16x8*)((const char*)WhiL + baddr);
        s16x8 bl = *(const s16x8*)((const char*)WloL + baddr);
        a0[j] = __builtin_amdgcn_mfma_f32_16x16x32_bf16(fh.h, bh, a0[j], 0, 0, 0);
        a1[j] = __builtin_amdgcn_mfma_f32_16x16x32_bf16(fh.h, bl, a1[j], 0, 0, 0);
        a2[j] = __builtin_amdgcn_mfma_f32_16x16x32_bf16(fl.h, bh, a2[j], 0, 0, 0);
      }
    }
#pragma unroll
    for (int j = 0; j < 2; ++j) {
      f32x4 zp = a0[j] + a1[j] + a2[j];
#pragma unroll
      for (int r = 0; r < 4; ++r)
        zred[t & 1][w][(lane >> 4) * 4 + r][j * 16 + arow] = zp[r];
    }
    __syncthreads();   // the only per-step barrier (zred double-buffered)

    // ---- elementwise update: thread owns (b_own, nabs0) and (b_own, nabs1) ----
    const float z0 = zred[t & 1][0][b_own][nl]      + zred[t & 1][1][b_own][nl]      +
                     zred[t & 1][2][b_own][nl]      + zred[t & 1][3][b_own][nl]      + w_c0;
    const float z1 = zred[t & 1][0][b_own][nl + 16] + zred[t & 1][1][b_own][nl + 16] +
                     zred[t & 1][2][b_own][nl + 16] + zred[t & 1][3][b_own][nl + 16] + w_c1;
    const float v0 = tanhf(z0), v1 = tanhf(z1);
    const float hn0 = a_c0 * hp0 + b_c0 * v0;
    const float hn1 = a_c1 * hp1 + b_c1 * v1;

    // publish FIRST (earliest possible visibility), outputs after
    if (t + 1 < T_STEPS) {
      const unsigned tagn = (unsigned)((t + 1) & 3);
      unsigned* nxt = hbp + (size_t)((t + 1) & 1) * BD + (long)b_own * 1024;
      __hip_atomic_store(&nxt[nabs0], pack_h(hn0, tagn), __ATOMIC_RELAXED, __HIP_MEMORY_SCOPE_AGENT);
      __hip_atomic_store(&nxt[nabs1], pack_h(hn1, tagn), __ATOMIC_RELAXED, __HIP_MEMORY_SCOPE_AGENT);
    }

    const long o = (long)t * BD;
    __builtin_nontemporal_store(hn0, h_out + BD + o + off0);
    __builtin_nontemporal_store(hn1, h_out + BD + o + off1);
    const float sg0 = 1.0f / (1.0f + __expf(-hn0));
    const float sg1 = 1.0f / (1.0f + __expf(-hn1));
    __builtin_nontemporal_store(hn0 * hn0 * sg0, out_buf + o + off0);
    __builtin_nontemporal_store(hn1 * hn1 * sg1, out_buf + o + off1);

    hp0 = hn0; hp1 = hn1;
    a_c0 = a_n0; a_c1 = a_n1; b_c0 = b_n0; b_c1 = b_n1; w_c0 = w_n0; w_c1 = w_n1;
  }
}

// ---------------- launch ----------------
extern "C" void kernel_launch(void* const* d_in, const int* in_sizes, int n_in,
                              void* d_out, int out_size, void* d_ws, size_t ws_size,
                              hipStream_t stream) {
  const float* x  = (const float*)d_in[0];
  const float* h0 = (const float*)d_in[1];
  const float* Wa = (const float*)d_in[2];
  const float* ba = (const float*)d_in[3];
  const float* Wb = (const float*)d_in[4];
  const float* bb = (const float*)d_in[5];
  const float* Wh = (const float*)d_in[6];
  const float* Wx = (const float*)d_in[7];
  const float* bx = (const float*)d_in[8];

  float* out_buf = (float*)d_out;
  float* h_out   = out_buf + OUT_ELEMS;

  char* ws = (char*)d_ws;
  float*          wx_buf = (float*)(ws + WX_OFF);
  unsigned short* xbf    = (unsigned short*)(ws + XBF_OFF);
  unsigned short* whi    = (unsigned short*)(ws + WHI_OFF);
  unsigned short* wlo    = (unsigned short*)(ws + WLO_OFF);
  unsigned*       hbp    = (unsigned*)(ws + HBP_OFF);

  convert_x_kernel<<<4096, 256, 0, stream>>>(x, xbf);
  convert_w_kernel<<<1024, 256, 0, stream>>>(Wa, Wb, Wx, whi, wlo);
  gemm_pre<<<dim3(256, 24), 256, 0, stream>>>(xbf, whi, wlo, ba, bb, bx,
                                              h_out + BD, out_buf, wx_buf);
  scan_kernel<<<32, 256, 0, stream>>>(Wh, h0, wx_buf, out_buf, h_out, hbp);
}

// Round 6
// 13008.929 us; speedup vs baseline: 1.4000x; 1.0889x over previous
//
#include <hip/hip_runtime.h>
#include <stdint.h>
#include <stddef.h>

// ---------------- problem constants ----------------
static constexpr int  T_STEPS   = 2048;
static constexpr int  BATCH     = 16;
static constexpr int  DIM       = 1024;
static constexpr long RROWS     = (long)T_STEPS * BATCH;   // 32768 rows of x
static constexpr long BD        = (long)BATCH * DIM;       // 16384
static constexpr long OUT_ELEMS = (long)T_STEPS * BD;      // 33554432

// ---------------- ws layout (bytes) ----------------
static constexpr size_t WX_OFF  = 0;
static constexpr size_t XBF_OFF = 134217728;
static constexpr size_t WHI_OFF = XBF_OFF + 67108864;   // 201326592
static constexpr size_t WLO_OFF = WHI_OFF + 6291456;    // 207618048
static constexpr size_t HBP_OFF = WLO_OFF + 6291456;    // 213909504: packed h [2][B][D] u32
static constexpr size_t FLG_OFF = HBP_OFF + 131072;     // 214040576: 128 per-wave flags

typedef __attribute__((ext_vector_type(4))) float          f32x4;
typedef __attribute__((ext_vector_type(8))) short          s16x8;
typedef __attribute__((ext_vector_type(4))) unsigned short u16x4;
typedef __attribute__((ext_vector_type(8))) unsigned short u16x8;

#define AS1 __attribute__((address_space(1)))
#define AS3 __attribute__((address_space(3)))

// ---------------- helpers ----------------
static __device__ __forceinline__ unsigned short f2bf(float x) {
  union { float f; unsigned u; } a; a.f = x;
  unsigned r = a.u + 0x7fffu + ((a.u >> 16) & 1u);
  return (unsigned short)(r >> 16);
}
static __device__ __forceinline__ float bf2f(unsigned short h) {
  union { unsigned u; float f; } a; a.u = ((unsigned)h) << 16; return a.f;
}
static __device__ __forceinline__ void gload_lds16(const void* g, void* l) {
  __builtin_amdgcn_global_load_lds((const AS1 void*)g, (AS3 void*)l, 16, 0, 0);
}
// packed h word: {bf16 hi | bf16 lo with 2 LSBs replaced by epoch tag}
static __device__ __forceinline__ unsigned pack_h(float hn, unsigned tag) {
  unsigned short hi = f2bf(hn);
  unsigned short lo = f2bf(hn - bf2f(hi));
  return ((unsigned)hi << 16) | (unsigned)(lo & 0xFFFCu) | tag;
}
static __device__ __forceinline__ float fast_tanh(float z) {
  // tanh(z) = 1 - 2/(exp(2z)+1); exp overflow/underflow saturate correctly
  return 1.0f - 2.0f / (__expf(2.0f * z) + 1.0f);
}

// ---------------- convert x -> bf16 ----------------
__global__ __launch_bounds__(256) void convert_x_kernel(const float* __restrict__ x,
                                                        unsigned short* __restrict__ xbf) {
  const long n8 = (RROWS * DIM) / 8;
  const long stride = (long)gridDim.x * blockDim.x;
  for (long i = (long)blockIdx.x * blockDim.x + threadIdx.x; i < n8; i += stride) {
    const float4* p = (const float4*)(x + i * 8);
    float4 v0 = p[0], v1 = p[1];
    u16x8 o;
    o[0] = f2bf(v0.x); o[1] = f2bf(v0.y); o[2] = f2bf(v0.z); o[3] = f2bf(v0.w);
    o[4] = f2bf(v1.x); o[5] = f2bf(v1.y); o[6] = f2bf(v1.z); o[7] = f2bf(v1.w);
    *(u16x8*)(xbf + i * 8) = o;
  }
}

// ---------------- convert [W_alpha;W_beta;W_x] -> bf16 hi/lo split ----------------
__global__ __launch_bounds__(256) void convert_w_kernel(const float* __restrict__ Wa,
                                                        const float* __restrict__ Wb,
                                                        const float* __restrict__ Wx,
                                                        unsigned short* __restrict__ whi,
                                                        unsigned short* __restrict__ wlo) {
  const long n4 = (3l * 1024 * 1024) / 4;
  const long stride = (long)gridDim.x * blockDim.x;
  for (long i = (long)blockIdx.x * blockDim.x + threadIdx.x; i < n4; i += stride) {
    long e = i * 4;
    int mat = (int)(e >> 20);
    long off = e & 1048575l;
    const float* src = (mat == 0) ? Wa : (mat == 1) ? Wb : Wx;
    float4 v = *(const float4*)(src + off);
    u16x4 hi, lo;
    hi[0] = f2bf(v.x); lo[0] = f2bf(v.x - bf2f(hi[0]));
    hi[1] = f2bf(v.y); lo[1] = f2bf(v.y - bf2f(hi[1]));
    hi[2] = f2bf(v.z); lo[2] = f2bf(v.z - bf2f(hi[2]));
    hi[3] = f2bf(v.w); lo[3] = f2bf(v.w - bf2f(hi[3]));
    *(u16x4*)(whi + e) = hi;
    *(u16x4*)(wlo + e) = lo;
  }
}

// ---------------- fused pre-GEMM: alpha/beta/wx = act(x @ Wcat^T + bias) ----------------
__global__ __launch_bounds__(256) void gemm_pre(
    const unsigned short* __restrict__ xbf,
    const unsigned short* __restrict__ whi,
    const unsigned short* __restrict__ wlo,
    const float* __restrict__ b_alpha, const float* __restrict__ b_beta, const float* __restrict__ b_x,
    float* __restrict__ alpha_dst, float* __restrict__ beta_dst, float* __restrict__ wx_dst)
{
  __shared__ unsigned short Al[128 * 64];
  __shared__ unsigned short Bh[128 * 64];
  __shared__ unsigned short Bl[128 * 64];
  const int tid  = threadIdx.x;
  const int lane = tid & 63;
  const int w    = tid >> 6;
  const int wm   = w >> 1, wn = w & 1;
  const long rowA0 = (long)blockIdx.x * 128;
  const int  colB0 = blockIdx.y * 128;

  f32x4 acc[4][4];
#pragma unroll
  for (int i = 0; i < 4; ++i)
#pragma unroll
    for (int j = 0; j < 4; ++j) acc[i][j] = (f32x4){0.f, 0.f, 0.f, 0.f};

  for (int k0 = 0; k0 < 1024; k0 += 64) {
#pragma unroll
    for (int is = 0; is < 4; ++is) {
      const int o   = is * 4096 + tid * 16;
      const int row = o >> 7;
      const int ke  = (o & 127) >> 1;
      const long asrc = (rowA0 + row) * 1024 + (k0 + ke);
      const long bsrc = ((long)(colB0 + row)) * 1024 + (k0 + ke);
      gload_lds16(xbf + asrc, (char*)Al + is * 4096 + w * 1024);
      gload_lds16(whi + bsrc, (char*)Bh + is * 4096 + w * 1024);
      gload_lds16(wlo + bsrc, (char*)Bl + is * 4096 + w * 1024);
    }
    asm volatile("s_waitcnt vmcnt(0)" ::: "memory");
    __syncthreads();
#pragma unroll
    for (int kk = 0; kk < 2; ++kk) {
      const int koff = kk * 64 + ((lane >> 4) * 16);
      s16x8 a[4], bhf[4], blf[4];
#pragma unroll
      for (int i = 0; i < 4; ++i)
        a[i] = *(const s16x8*)((const char*)Al + (wm * 64 + i * 16 + (lane & 15)) * 128 + koff);
#pragma unroll
      for (int j = 0; j < 4; ++j) {
        const int r = (wn * 64 + j * 16 + (lane & 15)) * 128 + koff;
        bhf[j] = *(const s16x8*)((const char*)Bh + r);
        blf[j] = *(const s16x8*)((const char*)Bl + r);
      }
#pragma unroll
      for (int i = 0; i < 4; ++i)
#pragma unroll
        for (int j = 0; j < 4; ++j) {
          acc[i][j] = __builtin_amdgcn_mfma_f32_16x16x32_bf16(a[i], bhf[j], acc[i][j], 0, 0, 0);
          acc[i][j] = __builtin_amdgcn_mfma_f32_16x16x32_bf16(a[i], blf[j], acc[i][j], 0, 0, 0);
        }
    }
    __syncthreads();
  }

  const int region = colB0 >> 10;
  const float* bias = (region == 0) ? b_alpha : (region == 1) ? b_beta : b_x;
  float* dst = (region == 0) ? alpha_dst : (region == 1) ? beta_dst : wx_dst;
#pragma unroll
  for (int j = 0; j < 4; ++j) {
    const int colg = colB0 + wn * 64 + j * 16 + (lane & 15);
    const int nl = colg & 1023;
    const float bj = bias[nl];
#pragma unroll
    for (int i = 0; i < 4; ++i) {
#pragma unroll
      for (int r = 0; r < 4; ++r) {
        const long rowg = rowA0 + wm * 64 + i * 16 + ((lane >> 4) * 4) + r;
        float z = acc[i][j][r] + bj;
        float val = (region == 2) ? z : (1.0f / (1.0f + __expf(-z)));
        dst[rowg * 1024 + nl] = val;
      }
    }
  }
}

// ---------------- persistent scan: thin-flag + tagged-payload protocol ----------------
// 32 WGs x 256 threads; WG owns channels [wg*32, wg*32+32).
// Producer wave: packed h stores (per-word epoch tag t&3) then lane0 stores its
// per-WAVE monotone flag — all fire-and-forget agent-relaxed (wave lockstep
// guarantees issue order; no vmcnt ack). Consumer wave w: polls ONE line
// (flags[w*32 + lane&31] — exactly its 32 producer waves), then loads the
// 16KB payload once; word tags verify freshness, rare patch-reload fixes
// flag-outruns-data races. Ping-pong buf[t&1] + mod-4 tags as in round 5
// (overwrite causally gated; poison/stale tags read as stale).
__global__ __launch_bounds__(256) void scan_kernel(
    const float* __restrict__ Wh,
    const float* __restrict__ h0,
    const float* __restrict__ wxb,
    float* __restrict__ out_buf,     // d_out: beta pre-stored here
    float* __restrict__ h_out,       // d_out + OUT_ELEMS: alpha pre-stored at +BD
    unsigned* __restrict__ hbp,      // packed h ping-pong [2][B][D]
    int* __restrict__ flags)         // 128 per-wave flags (memset 0 per launch)
{
  __shared__ unsigned short WhiL[32 * 1024];
  __shared__ unsigned short WloL[32 * 1024];
  __shared__ float zred[2][4][16][48];   // stride 48: 2-way (free) LDS banking

  const int tid  = threadIdx.x;
  const int lane = tid & 63;
  const int w    = tid >> 6;
  const int wg   = blockIdx.x;
  const int n0   = wg * 32;

  // ---- stage W_h slice (32 rows) into LDS, hi/lo bf16, XOR-swizzled ----
  {
    const int row = tid >> 3;            // 0..31
    const int kb  = (tid & 7) * 128;     // 128 elems per thread
    const float* src = Wh + (size_t)(n0 + row) * 1024 + kb;
    const unsigned sx = ((unsigned)(row & 7)) << 4;
    const unsigned rb = (unsigned)row * 2048u;
#pragma unroll
    for (int q = 0; q < 32; ++q) {
      float4 v = *(const float4*)(src + q * 4);
      u16x4 hi, lo;
      hi[0] = f2bf(v.x); lo[0] = f2bf(v.x - bf2f(hi[0]));
      hi[1] = f2bf(v.y); lo[1] = f2bf(v.y - bf2f(hi[1]));
      hi[2] = f2bf(v.z); lo[2] = f2bf(v.z - bf2f(hi[2]));
      hi[3] = f2bf(v.w); lo[3] = f2bf(v.w - bf2f(hi[3]));
      const unsigned addr = (rb + (unsigned)(kb + q * 4) * 2u) ^ sx;
      *(u16x4*)((char*)WhiL + addr) = hi;
      *(u16x4*)((char*)WloL + addr) = lo;
    }
  }

  const int b_own = tid >> 4;            // batch 0..15
  const int nl    = tid & 15;            // channel-within-slice (plus +16 twin)
  const int nabs0 = n0 + nl, nabs1 = n0 + nl + 16;
  const long off0 = (long)b_own * 1024 + nabs0;
  const long off1 = off0 + 16;

  // ---- phase 0: h[0] = h0, publish packed words (tag 0), raise wave flag ----
  float hp0 = h0[off0], hp1 = h0[off1];
  h_out[off0] = hp0; h_out[off1] = hp1;
  {
    unsigned* b0 = hbp + (long)b_own * 1024;
    __hip_atomic_store(&b0[nabs0], pack_h(hp0, 0u), __ATOMIC_RELAXED, __HIP_MEMORY_SCOPE_AGENT);
    __hip_atomic_store(&b0[nabs1], pack_h(hp1, 0u), __ATOMIC_RELAXED, __HIP_MEMORY_SCOPE_AGENT);
  }
  if (lane == 0)
    __hip_atomic_store(&flags[wg * 4 + w], 1, __ATOMIC_RELAXED, __HIP_MEMORY_SCOPE_AGENT);
  __syncthreads();   // LDS W staging complete

  // gates for t=0 (alpha pre-stored in h[t+1] slots, beta in out[t] slots)
  float a_c0 = h_out[BD + off0], a_c1 = h_out[BD + off1];
  float b_c0 = out_buf[off0],    b_c1 = out_buf[off1];
  float w_c0 = wxb[off0],        w_c1 = wxb[off1];

  const int arow = lane & 15;                      // batch (A row) / channel col
  const int kq   = w * 256 + ((lane >> 4) * 8);    // wave's K-quarter, lane's k base
  const unsigned bswz = ((unsigned)(arow & 7)) << 4;
  const int* fp = flags + w * 32 + (lane & 31);    // this wave's 32 producer-wave flags

  for (int t = 0; t < T_STEPS; ++t) {
    // prefetch next step's gates (overlaps the poll)
    float a_n0 = 0.f, a_n1 = 0.f, b_n0 = 0.f, b_n1 = 0.f, w_n0 = 0.f, w_n1 = 0.f;
    if (t + 1 < T_STEPS) {
      const long o = (long)(t + 1) * BD;
      a_n0 = __builtin_nontemporal_load(h_out + BD + o + off0);
      a_n1 = __builtin_nontemporal_load(h_out + BD + o + off1);
      b_n0 = __builtin_nontemporal_load(out_buf + o + off0);
      b_n1 = __builtin_nontemporal_load(out_buf + o + off1);
      w_n0 = __builtin_nontemporal_load(wxb + o + off0);
      w_n1 = __builtin_nontemporal_load(wxb + o + off1);
    }

    // ---- thin poll: one line of per-wave flags ----
    {
      int iters = 0;
      while (true) {
        int f = __hip_atomic_load(fp, __ATOMIC_RELAXED, __HIP_MEMORY_SCOPE_AGENT);
        if (__all(f >= t + 1)) break;
        if (++iters > (1 << 16)) break;   // safety valve: visible failure beats a hang
      }
    }

    // ---- payload: load fragment once; verify word tags; patch-reload if racing ----
    const unsigned tagt = (unsigned)(t & 3);
    const unsigned* cur = hbp + (size_t)(t & 1) * BD + ((long)arow << 10) + kq;
    unsigned long long v[32];
    {
      int iters = 0;
      while (true) {
        unsigned bad = 0;
#pragma unroll
        for (int s = 0; s < 8; ++s) {
          const unsigned long long* p = (const unsigned long long*)(cur + s * 32);
          v[s*4+0] = __hip_atomic_load(p + 0, __ATOMIC_RELAXED, __HIP_MEMORY_SCOPE_AGENT);
          v[s*4+1] = __hip_atomic_load(p + 1, __ATOMIC_RELAXED, __HIP_MEMORY_SCOPE_AGENT);
          v[s*4+2] = __hip_atomic_load(p + 2, __ATOMIC_RELAXED, __HIP_MEMORY_SCOPE_AGENT);
          v[s*4+3] = __hip_atomic_load(p + 3, __ATOMIC_RELAXED, __HIP_MEMORY_SCOPE_AGENT);
        }
#pragma unroll
        for (int i = 0; i < 32; ++i) {
          bad |= ((unsigned)v[i] ^ tagt) & 3u;
          bad |= ((unsigned)(v[i] >> 32) ^ tagt) & 3u;
        }
        if (__all(bad == 0u)) break;          // expected on first pass
        if (++iters > 4096) break;            // safety valve
        __builtin_amdgcn_s_sleep(1);
      }
    }

    // ---- unpack {hi,lo} + z = h @ Wh_slice^T (3-term bf16 split, 2 col-tiles) ----
    f32x4 a0[2], a1[2], a2[2];
#pragma unroll
    for (int j = 0; j < 2; ++j) {
      a0[j] = (f32x4){0.f,0.f,0.f,0.f};
      a1[j] = (f32x4){0.f,0.f,0.f,0.f};
      a2[j] = (f32x4){0.f,0.f,0.f,0.f};
    }
    union Frag { unsigned d[4]; s16x8 h; };
#pragma unroll
    for (int s = 0; s < 8; ++s) {
      Frag fh, fl;
#pragma unroll
      for (int q2 = 0; q2 < 4; ++q2) {
        const unsigned w0 = (unsigned)v[s*4+q2];
        const unsigned w1 = (unsigned)(v[s*4+q2] >> 32);
        fh.d[q2] = (w0 >> 16) | (w1 & 0xFFFF0000u);
        fl.d[q2] = (w0 & 0xFFFCu) | ((w1 & 0xFFFCu) << 16);
      }
      const int ko = kq + s * 32;
#pragma unroll
      for (int j = 0; j < 2; ++j) {
        const unsigned baddr = (((unsigned)(j * 16 + arow)) * 2048u + (unsigned)ko * 2u) ^ bswz;
        s16x8 bh = *(const s16x8*)((const char*)WhiL + baddr);
        s16x8 bl = *(const s16x8*)((const char*)WloL + baddr);
        a0[j] = __builtin_amdgcn_mfma_f32_16x16x32_bf16(fh.h, bh, a0[j], 0, 0, 0);
        a1[j] = __builtin_amdgcn_mfma_f32_16x16x32_bf16(fh.h, bl, a1[j], 0, 0, 0);
        a2[j] = __builtin_amdgcn_mfma_f32_16x16x32_bf16(fl.h, bh, a2[j], 0, 0, 0);
      }
    }
#pragma unroll
    for (int j = 0; j < 2; ++j) {
      f32x4 zp = a0[j] + a1[j] + a2[j];
#pragma unroll
      for (int r = 0; r < 4; ++r)
        zred[t & 1][w][(lane >> 4) * 4 + r][j * 16 + arow] = zp[r];
    }
    __syncthreads();   // the only per-step barrier (zred double-buffered)

    // ---- elementwise update: thread owns (b_own, nabs0) and (b_own, nabs1) ----
    const float z0 = zred[t & 1][0][b_own][nl]      + zred[t & 1][1][b_own][nl]      +
                     zred[t & 1][2][b_own][nl]      + zred[t & 1][3][b_own][nl]      + w_c0;
    const float z1 = zred[t & 1][0][b_own][nl + 16] + zred[t & 1][1][b_own][nl + 16] +
                     zred[t & 1][2][b_own][nl + 16] + zred[t & 1][3][b_own][nl + 16] + w_c1;
    const float v0 = fast_tanh(z0), v1 = fast_tanh(z1);
    const float hn0 = a_c0 * hp0 + b_c0 * v0;
    const float hn1 = a_c1 * hp1 + b_c1 * v1;

    // publish data then this wave's flag (issue-ordered within the wave)
    if (t + 1 < T_STEPS) {
      const unsigned tagn = (unsigned)((t + 1) & 3);
      unsigned* nxt = hbp + (size_t)((t + 1) & 1) * BD + (long)b_own * 1024;
      __hip_atomic_store(&nxt[nabs0], pack_h(hn0, tagn), __ATOMIC_RELAXED, __HIP_MEMORY_SCOPE_AGENT);
      __hip_atomic_store(&nxt[nabs1], pack_h(hn1, tagn), __ATOMIC_RELAXED, __HIP_MEMORY_SCOPE_AGENT);
      if (lane == 0)
        __hip_atomic_store(&flags[wg * 4 + w], t + 2, __ATOMIC_RELAXED, __HIP_MEMORY_SCOPE_AGENT);
    }

    const long o = (long)t * BD;
    __builtin_nontemporal_store(hn0, h_out + BD + o + off0);
    __builtin_nontemporal_store(hn1, h_out + BD + o + off1);
    const float sg0 = 1.0f / (1.0f + __expf(-hn0));
    const float sg1 = 1.0f / (1.0f + __expf(-hn1));
    __builtin_nontemporal_store(hn0 * hn0 * sg0, out_buf + o + off0);
    __builtin_nontemporal_store(hn1 * hn1 * sg1, out_buf + o + off1);

    hp0 = hn0; hp1 = hn1;
    a_c0 = a_n0; a_c1 = a_n1; b_c0 = b_n0; b_c1 = b_n1; w_c0 = w_n0; w_c1 = w_n1;
  }
}

// ---------------- launch ----------------
extern "C" void kernel_launch(void* const* d_in, const int* in_sizes, int n_in,
                              void* d_out, int out_size, void* d_ws, size_t ws_size,
                              hipStream_t stream) {
  const float* x  = (const float*)d_in[0];
  const float* h0 = (const float*)d_in[1];
  const float* Wa = (const float*)d_in[2];
  const float* ba = (const float*)d_in[3];
  const float* Wb = (const float*)d_in[4];
  const float* bb = (const float*)d_in[5];
  const float* Wh = (const float*)d_in[6];
  const float* Wx = (const float*)d_in[7];
  const float* bx = (const float*)d_in[8];

  float* out_buf = (float*)d_out;
  float* h_out   = out_buf + OUT_ELEMS;

  char* ws = (char*)d_ws;
  float*          wx_buf = (float*)(ws + WX_OFF);
  unsigned short* xbf    = (unsigned short*)(ws + XBF_OFF);
  unsigned short* whi    = (unsigned short*)(ws + WHI_OFF);
  unsigned short* wlo    = (unsigned short*)(ws + WLO_OFF);
  unsigned*       hbp    = (unsigned*)(ws + HBP_OFF);
  int*            flags  = (int*)(ws + FLG_OFF);

  hipMemsetAsync(flags, 0, 512, stream);   // flags reset every launch/replay
  convert_x_kernel<<<4096, 256, 0, stream>>>(x, xbf);
  convert_w_kernel<<<1024, 256, 0, stream>>>(Wa, Wb, Wx, whi, wlo);
  gemm_pre<<<dim3(256, 24), 256, 0, stream>>>(xbf, whi, wlo, ba, bb, bx,
                                              h_out + BD, out_buf, wx_buf);
  scan_kernel<<<32, 256, 0, stream>>>(Wh, h0, wx_buf, out_buf, h_out, hbp, flags);
}

// Round 8
// 11315.596 us; speedup vs baseline: 1.6095x; 1.1496x over previous
//
#include <hip/hip_runtime.h>
#include <stdint.h>
#include <stddef.h>

// ---------------- problem constants ----------------
static constexpr int  T_STEPS   = 2048;
static constexpr int  BATCH     = 16;
static constexpr int  DIM       = 1024;
static constexpr long RROWS     = (long)T_STEPS * BATCH;   // 32768 rows of x
static constexpr long BD        = (long)BATCH * DIM;       // 16384
static constexpr long OUT_ELEMS = (long)T_STEPS * BD;      // 33554432

// ---------------- ws layout (bytes) ----------------
static constexpr size_t WX_OFF  = 0;
static constexpr size_t XBF_OFF = 134217728;
static constexpr size_t WHI_OFF = XBF_OFF + 67108864;   // 201326592
static constexpr size_t WLO_OFF = WHI_OFF + 6291456;    // 207618048
static constexpr size_t HBP_OFF = WLO_OFF + 6291456;    // 213909504: packed h [2][B][D] u32

typedef __attribute__((ext_vector_type(2))) float          f32x2;
typedef __attribute__((ext_vector_type(4))) float          f32x4;
typedef __attribute__((ext_vector_type(8))) short          s16x8;
typedef __attribute__((ext_vector_type(4))) unsigned short u16x4;
typedef __attribute__((ext_vector_type(8))) unsigned short u16x8;

#define AS1 __attribute__((address_space(1)))
#define AS3 __attribute__((address_space(3)))

// ---------------- helpers ----------------
static __device__ __forceinline__ unsigned short f2bf(float x) {
  union { float f; unsigned u; } a; a.f = x;
  unsigned r = a.u + 0x7fffu + ((a.u >> 16) & 1u);
  return (unsigned short)(r >> 16);
}
static __device__ __forceinline__ float bf2f(unsigned short h) {
  union { unsigned u; float f; } a; a.u = ((unsigned)h) << 16; return a.f;
}
static __device__ __forceinline__ void gload_lds16(const void* g, void* l) {
  __builtin_amdgcn_global_load_lds((const AS1 void*)g, (AS3 void*)l, 16, 0, 0);
}
static __device__ __forceinline__ float fast_tanh(float z) {
  return 1.0f - 2.0f / (__expf(2.0f * z) + 1.0f);
}

// ---------------- convert x -> bf16 ----------------
__global__ __launch_bounds__(256) void convert_x_kernel(const float* __restrict__ x,
                                                        unsigned short* __restrict__ xbf) {
  const long n8 = (RROWS * DIM) / 8;
  const long stride = (long)gridDim.x * blockDim.x;
  for (long i = (long)blockIdx.x * blockDim.x + threadIdx.x; i < n8; i += stride) {
    const float4* p = (const float4*)(x + i * 8);
    float4 v0 = p[0], v1 = p[1];
    u16x8 o;
    o[0] = f2bf(v0.x); o[1] = f2bf(v0.y); o[2] = f2bf(v0.z); o[3] = f2bf(v0.w);
    o[4] = f2bf(v1.x); o[5] = f2bf(v1.y); o[6] = f2bf(v1.z); o[7] = f2bf(v1.w);
    *(u16x8*)(xbf + i * 8) = o;
  }
}

// ---------------- convert [W_alpha;W_beta;W_x] -> bf16 hi/lo split ----------------
__global__ __launch_bounds__(256) void convert_w_kernel(const float* __restrict__ Wa,
                                                        const float* __restrict__ Wb,
                                                        const float* __restrict__ Wx,
                                                        unsigned short* __restrict__ whi,
                                                        unsigned short* __restrict__ wlo) {
  const long n4 = (3l * 1024 * 1024) / 4;
  const long stride = (long)gridDim.x * blockDim.x;
  for (long i = (long)blockIdx.x * blockDim.x + threadIdx.x; i < n4; i += stride) {
    long e = i * 4;
    int mat = (int)(e >> 20);
    long off = e & 1048575l;
    const float* src = (mat == 0) ? Wa : (mat == 1) ? Wb : Wx;
    float4 v = *(const float4*)(src + off);
    u16x4 hi, lo;
    hi[0] = f2bf(v.x); lo[0] = f2bf(v.x - bf2f(hi[0]));
    hi[1] = f2bf(v.y); lo[1] = f2bf(v.y - bf2f(hi[1]));
    hi[2] = f2bf(v.z); lo[2] = f2bf(v.z - bf2f(hi[2]));
    hi[3] = f2bf(v.w); lo[3] = f2bf(v.w - bf2f(hi[3]));
    *(u16x4*)(whi + e) = hi;
    *(u16x4*)(wlo + e) = lo;
  }
}

// ---------------- fused pre-GEMM: alpha/beta/wx = act(x @ Wcat^T + bias) ----------------
__global__ __launch_bounds__(256) void gemm_pre(
    const unsigned short* __restrict__ xbf,
    const unsigned short* __restrict__ whi,
    const unsigned short* __restrict__ wlo,
    const float* __restrict__ b_alpha, const float* __restrict__ b_beta, const float* __restrict__ b_x,
    float* __restrict__ alpha_dst, float* __restrict__ beta_dst, float* __restrict__ wx_dst)
{
  __shared__ unsigned short Al[128 * 64];
  __shared__ unsigned short Bh[128 * 64];
  __shared__ unsigned short Bl[128 * 64];
  const int tid  = threadIdx.x;
  const int lane = tid & 63;
  const int w    = tid >> 6;
  const int wm   = w >> 1, wn = w & 1;
  const long rowA0 = (long)blockIdx.x * 128;
  const int  colB0 = blockIdx.y * 128;

  f32x4 acc[4][4];
#pragma unroll
  for (int i = 0; i < 4; ++i)
#pragma unroll
    for (int j = 0; j < 4; ++j) acc[i][j] = (f32x4){0.f, 0.f, 0.f, 0.f};

  for (int k0 = 0; k0 < 1024; k0 += 64) {
#pragma unroll
    for (int is = 0; is < 4; ++is) {
      const int o   = is * 4096 + tid * 16;
      const int row = o >> 7;
      const int ke  = (o & 127) >> 1;
      const long asrc = (rowA0 + row) * 1024 + (k0 + ke);
      const long bsrc = ((long)(colB0 + row)) * 1024 + (k0 + ke);
      gload_lds16(xbf + asrc, (char*)Al + is * 4096 + w * 1024);
      gload_lds16(whi + bsrc, (char*)Bh + is * 4096 + w * 1024);
      gload_lds16(wlo + bsrc, (char*)Bl + is * 4096 + w * 1024);
    }
    asm volatile("s_waitcnt vmcnt(0)" ::: "memory");
    __syncthreads();
#pragma unroll
    for (int kk = 0; kk < 2; ++kk) {
      const int koff = kk * 64 + ((lane >> 4) * 16);
      s16x8 a[4], bhf[4], blf[4];
#pragma unroll
      for (int i = 0; i < 4; ++i)
        a[i] = *(const s16x8*)((const char*)Al + (wm * 64 + i * 16 + (lane & 15)) * 128 + koff);
#pragma unroll
      for (int j = 0; j < 4; ++j) {
        const int r = (wn * 64 + j * 16 + (lane & 15)) * 128 + koff;
        bhf[j] = *(const s16x8*)((const char*)Bh + r);
        blf[j] = *(const s16x8*)((const char*)Bl + r);
      }
#pragma unroll
      for (int i = 0; i < 4; ++i)
#pragma unroll
        for (int j = 0; j < 4; ++j) {
          acc[i][j] = __builtin_amdgcn_mfma_f32_16x16x32_bf16(a[i], bhf[j], acc[i][j], 0, 0, 0);
          acc[i][j] = __builtin_amdgcn_mfma_f32_16x16x32_bf16(a[i], blf[j], acc[i][j], 0, 0, 0);
        }
    }
    __syncthreads();
  }

  const int region = colB0 >> 10;
  const float* bias = (region == 0) ? b_alpha : (region == 1) ? b_beta : b_x;
  float* dst = (region == 0) ? alpha_dst : (region == 1) ? beta_dst : wx_dst;
#pragma unroll
  for (int j = 0; j < 4; ++j) {
    const int colg = colB0 + wn * 64 + j * 16 + (lane & 15);
    const int nl = colg & 1023;
    const float bj = bias[nl];
#pragma unroll
    for (int i = 0; i < 4; ++i) {
#pragma unroll
      for (int r = 0; r < 4; ++r) {
        const long rowg = rowA0 + wm * 64 + i * 16 + ((lane >> 4) * 4) + r;
        float z = acc[i][j][r] + bj;
        float val = (region == 2) ? z : (1.0f / (1.0f + __expf(-z)));
        dst[rowg * 1024 + nl] = val;
      }
    }
  }
}

// ---------------- persistent scan: chunk-granular data-as-flag, loads-first ----------------
// 32 WGs x 256 threads; WG owns channels [wg*32, wg*32+32).
// h word = {bf16(h) << 16 | epoch tag (t&3)} stored via agent-relaxed atomics.
// Consumer wave w: k-chunk q depends EXACTLY on producer WG w*8+q. All 8 chunk
// loads are issued branch-free at step top (no flags, no poll hop); per-chunk
// tag verify; fresh chunks MFMA immediately; stale chunks retried individually
// (32B/lane). 2-term split MFMA: z = bf16(h) * (Whi + Wlo); the dropped
// lo(h)*Whi term random-walks to ~1e-3 -- invisible under the 0.25 bf16 floor.
// Ping-pong buf[t&1] + mod-4 tags give causal overwrite safety and make 0xAA
// poison / previous-replay leftovers read as stale (tags 2/3 vs expected 0/1).
__global__ __launch_bounds__(256, 1) void scan_kernel(
    const float* __restrict__ Wh,
    const float* __restrict__ h0,
    const float* __restrict__ wxb,
    float* __restrict__ out_buf,     // d_out: beta pre-stored here
    float* __restrict__ h_out,       // d_out + OUT_ELEMS: alpha pre-stored at +BD
    unsigned* __restrict__ hbp)      // packed h ping-pong [2][B][D]
{
  __shared__ unsigned short WhiL[32 * 1024];
  __shared__ unsigned short WloL[32 * 1024];
  __shared__ __align__(16) float zred[2][4][16][34];

  const int tid  = threadIdx.x;
  const int lane = tid & 63;
  const int w    = tid >> 6;
  const int wg   = blockIdx.x;
  const int n0   = wg * 32;

  // ---- stage W_h slice (32 rows) into LDS, hi/lo bf16, XOR-swizzled ----
  {
    const int row = tid >> 3;            // 0..31
    const int kb  = (tid & 7) * 128;     // 128 elems per thread
    const float* src = Wh + (size_t)(n0 + row) * 1024 + kb;
    const unsigned sx = ((unsigned)(row & 7)) << 4;
    const unsigned rb = (unsigned)row * 2048u;
#pragma unroll
    for (int q = 0; q < 32; ++q) {
      float4 v = *(const float4*)(src + q * 4);
      u16x4 hi, lo;
      hi[0] = f2bf(v.x); lo[0] = f2bf(v.x - bf2f(hi[0]));
      hi[1] = f2bf(v.y); lo[1] = f2bf(v.y - bf2f(hi[1]));
      hi[2] = f2bf(v.z); lo[2] = f2bf(v.z - bf2f(hi[2]));
      hi[3] = f2bf(v.w); lo[3] = f2bf(v.w - bf2f(hi[3]));
      const unsigned addr = (rb + (unsigned)(kb + q * 4) * 2u) ^ sx;
      *(u16x4*)((char*)WhiL + addr) = hi;
      *(u16x4*)((char*)WloL + addr) = lo;
    }
  }

  // elementwise ownership: thread owns (b_own, channels ch0=n0+2nl, ch1=ch0+1)
  const int b_own = tid >> 4;            // batch 0..15
  const int nl    = tid & 15;            // channel-pair id
  const int ch0   = n0 + 2 * nl;
  const long off0 = (long)b_own * 1024 + ch0;   // +1 gives ch1

  // MFMA operand roles
  const int arow = lane & 15;                      // A row (batch) / B col (channel)
  const int gk   = lane >> 4;                      // k subgroup
  const unsigned bswz = ((unsigned)(arow & 7)) << 4;

  // ---- phase 0: h[0] = h0, publish packed words (tag 0) into buf 0 ----
  f32x2 hpv = *(const f32x2*)(h0 + off0);
  float hp0 = hpv[0], hp1 = hpv[1];
  *(f32x2*)(h_out + off0) = hpv;
  {
    unsigned long long pv = (unsigned long long)(((unsigned)f2bf(hp0) << 16) | 0u)
                          | ((unsigned long long)(((unsigned)f2bf(hp1) << 16) | 0u) << 32);
    __hip_atomic_store((unsigned long long*)hbp + (off0 >> 1), pv,
                       __ATOMIC_RELAXED, __HIP_MEMORY_SCOPE_AGENT);
  }
  __syncthreads();   // W LDS staging complete

  // gates for t=0 (alpha pre-stored in h[t+1] slots, beta in out[t] slots)
  f32x2 acv = *(const f32x2*)(h_out + BD + off0);
  f32x2 bcv = *(const f32x2*)(out_buf + off0);
  f32x2 wcv = *(const f32x2*)(wxb + off0);
  float a_c0 = acv[0], a_c1 = acv[1], b_c0 = bcv[0], b_c1 = bcv[1], w_c0 = wcv[0], w_c1 = wcv[1];

  for (int t = 0; t < T_STEPS; ++t) {
    const unsigned tagt = (unsigned)(t & 3);
    // chunk q (q=0..7) <-> producer WG w*8+q; per lane: 8 u32 = 4 u64 contiguous
    const unsigned long long* base64 =
        (const unsigned long long*)hbp +
        (((size_t)(t & 1) * BD + (long)arow * 1024 + w * 256 + gk * 8) >> 1);

    // ---- issue ALL chunk loads branch-free (data arrives while we verify) ----
    unsigned long long vv[8][4];
#pragma unroll
    for (int q = 0; q < 8; ++q)
#pragma unroll
      for (int d = 0; d < 4; ++d)
        vv[q][d] = __hip_atomic_load(base64 + q * 16 + d,
                                     __ATOMIC_RELAXED, __HIP_MEMORY_SCOPE_AGENT);

    // prefetch next step's gates (f32x2 x3, NT) — overlaps chunk latency
    float a_n0 = 0.f, a_n1 = 0.f, b_n0 = 0.f, b_n1 = 0.f, w_n0 = 0.f, w_n1 = 0.f;
    if (t + 1 < T_STEPS) {
      const long o = (long)(t + 1) * BD + off0;
      f32x2 an = __builtin_nontemporal_load((const f32x2*)(h_out + BD + o));
      f32x2 bn = __builtin_nontemporal_load((const f32x2*)(out_buf + o));
      f32x2 wn = __builtin_nontemporal_load((const f32x2*)(wxb + o));
      a_n0 = an[0]; a_n1 = an[1]; b_n0 = bn[0]; b_n1 = bn[1]; w_n0 = wn[0]; w_n1 = wn[1];
    }

    f32x4 acc0 = (f32x4){0.f,0.f,0.f,0.f};
    f32x4 acc1 = (f32x4){0.f,0.f,0.f,0.f};
    const unsigned kbase = (unsigned)(w * 256 + gk * 8) * 2u;   // byte offset in W row
    union Frag { unsigned u[4]; s16x8 h; };

#define DO_CHUNK(Q, V)                                                          \
    {                                                                           \
      Frag fh;                                                                  \
      _Pragma("unroll")                                                         \
      for (int d = 0; d < 4; ++d) {                                             \
        const unsigned lo32 = (unsigned)(V)[d];                                 \
        const unsigned hi32 = (unsigned)((V)[d] >> 32);                         \
        fh.u[d] = (lo32 >> 16) | (hi32 & 0xFFFF0000u);                          \
      }                                                                         \
      const unsigned kb = kbase + (unsigned)(Q) * 64u;                          \
      const unsigned a0 = ((unsigned)arow * 2048u + kb) ^ bswz;                 \
      const unsigned a1 = ((unsigned)(16 + arow) * 2048u + kb) ^ bswz;          \
      s16x8 bh0 = *(const s16x8*)((const char*)WhiL + a0);                      \
      s16x8 bl0 = *(const s16x8*)((const char*)WloL + a0);                      \
      s16x8 bh1 = *(const s16x8*)((const char*)WhiL + a1);                      \
      s16x8 bl1 = *(const s16x8*)((const char*)WloL + a1);                      \
      acc0 = __builtin_amdgcn_mfma_f32_16x16x32_bf16(fh.h, bh0, acc0, 0, 0, 0); \
      acc0 = __builtin_amdgcn_mfma_f32_16x16x32_bf16(fh.h, bl0, acc0, 0, 0, 0); \
      acc1 = __builtin_amdgcn_mfma_f32_16x16x32_bf16(fh.h, bh1, acc1, 0, 0, 0); \
      acc1 = __builtin_amdgcn_mfma_f32_16x16x32_bf16(fh.h, bl1, acc1, 0, 0, 0); \
    }

    // ---- verify + MFMA fresh chunks; collect stragglers ----
    unsigned pend = 0;
#pragma unroll
    for (int q = 0; q < 8; ++q) {
      unsigned bad = 0;
#pragma unroll
      for (int d = 0; d < 4; ++d) {
        bad |= ((unsigned)vv[q][d] ^ tagt) & 3u;
        bad |= ((unsigned)(vv[q][d] >> 32) ^ tagt) & 3u;
      }
      if (__all(bad == 0u)) { DO_CHUNK(q, vv[q]); }
      else                  { pend |= 1u << q; }
    }

    // ---- straggler retry: reload only pending chunks ----
    int iters = 0;
    while (pend) {
#pragma unroll
      for (int q = 0; q < 8; ++q) {
        if (pend & (1u << q)) {
          unsigned long long nv[4];
#pragma unroll
          for (int d = 0; d < 4; ++d)
            nv[d] = __hip_atomic_load(base64 + q * 16 + d,
                                      __ATOMIC_RELAXED, __HIP_MEMORY_SCOPE_AGENT);
          unsigned bad = 0;
#pragma unroll
          for (int d = 0; d < 4; ++d) {
            bad |= ((unsigned)nv[d] ^ tagt) & 3u;
            bad |= ((unsigned)(nv[d] >> 32) ^ tagt) & 3u;
          }
          if (__all(bad == 0u)) { DO_CHUNK(q, nv); pend &= ~(1u << q); }
        }
      }
      if (++iters > (1 << 15)) break;   // safety valve: visible failure beats a hang
    }
#undef DO_CHUNK

    // ---- cross-wave K reduction via LDS ----
    const int tb = t & 1;
#pragma unroll
    for (int r = 0; r < 4; ++r) {
      zred[tb][w][gk * 4 + r][arow]      = acc0[r];
      zred[tb][w][gk * 4 + r][16 + arow] = acc1[r];
    }
    __syncthreads();   // the only per-step barrier (zred double-buffered)

    // ---- elementwise update for (b_own, ch0) and (b_own, ch1) ----
    float z0 = w_c0, z1 = w_c1;
#pragma unroll
    for (int wv = 0; wv < 4; ++wv) {
      f32x2 p = *(const f32x2*)&zred[tb][wv][b_own][2 * nl];
      z0 += p[0]; z1 += p[1];
    }
    const float v0 = fast_tanh(z0), v1 = fast_tanh(z1);
    const float hn0 = a_c0 * hp0 + b_c0 * v0;
    const float hn1 = a_c1 * hp1 + b_c1 * v1;

    // publish FIRST (earliest visibility) — one u64 per thread, no shuffles
    if (t + 1 < T_STEPS) {
      const unsigned tagn = (unsigned)((t + 1) & 3);
      unsigned long long pv =
          (unsigned long long)(((unsigned)f2bf(hn0) << 16) | tagn)
        | ((unsigned long long)(((unsigned)f2bf(hn1) << 16) | tagn) << 32);
      __hip_atomic_store((unsigned long long*)hbp + (((size_t)((t + 1) & 1) * BD + off0) >> 1),
                         pv, __ATOMIC_RELAXED, __HIP_MEMORY_SCOPE_AGENT);
    }

    // final outputs (f32x2 NT, off the critical path)
    const long o = (long)t * BD + off0;
    f32x2 hv; hv[0] = hn0; hv[1] = hn1;
    __builtin_nontemporal_store(hv, (f32x2*)(h_out + BD + o));
    const float sg0 = 1.0f / (1.0f + __expf(-hn0));
    const float sg1 = 1.0f / (1.0f + __expf(-hn1));
    f32x2 ov; ov[0] = hn0 * hn0 * sg0; ov[1] = hn1 * hn1 * sg1;
    __builtin_nontemporal_store(ov, (f32x2*)(out_buf + o));

    hp0 = hn0; hp1 = hn1;
    a_c0 = a_n0; a_c1 = a_n1; b_c0 = b_n0; b_c1 = b_n1; w_c0 = w_n0; w_c1 = w_n1;
  }
}

// ---------------- launch ----------------
extern "C" void kernel_launch(void* const* d_in, const int* in_sizes, int n_in,
                              void* d_out, int out_size, void* d_ws, size_t ws_size,
                              hipStream_t stream) {
  const float* x  = (const float*)d_in[0];
  const float* h0 = (const float*)d_in[1];
  const float* Wa = (const float*)d_in[2];
  const float* ba = (const float*)d_in[3];
  const float* Wb = (const float*)d_in[4];
  const float* bb = (const float*)d_in[5];
  const float* Wh = (const float*)d_in[6];
  const float* Wx = (const float*)d_in[7];
  const float* bx = (const float*)d_in[8];

  float* out_buf = (float*)d_out;
  float* h_out   = out_buf + OUT_ELEMS;

  char* ws = (char*)d_ws;
  float*          wx_buf = (float*)(ws + WX_OFF);
  unsigned short* xbf    = (unsigned short*)(ws + XBF_OFF);
  unsigned short* whi    = (unsigned short*)(ws + WHI_OFF);
  unsigned short* wlo    = (unsigned short*)(ws + WLO_OFF);
  unsigned*       hbp    = (unsigned*)(ws + HBP_OFF);

  convert_x_kernel<<<4096, 256, 0, stream>>>(x, xbf);
  convert_w_kernel<<<1024, 256, 0, stream>>>(Wa, Wb, Wx, whi, wlo);
  gemm_pre<<<dim3(256, 24), 256, 0, stream>>>(xbf, whi, wlo, ba, bb, bx,
                                              h_out + BD, out_buf, wx_buf);
  scan_kernel<<<32, 256, 0, stream>>>(Wh, h0, wx_buf, out_buf, h_out, hbp);
}